// Round 1
// baseline (278.623 us; speedup 1.0000x reference)
//
#include <hip/hip_runtime.h>

#define HID 256
#define K27 27

// v1: fused fp32 VALU baseline.
// One thread per output pixel. W1|b1 and W2^T staged in LDS (uniform-address
// broadcast reads across the wave -> no bank conflicts). lw[27] in registers.
// Gather uses clamped addresses + select so no speculative OOB loads.
__global__ __launch_bounds__(256) void mapnet_fused(
    const float* __restrict__ pos,      // (P,3)
    const int*   __restrict__ mapping,  // (P,2) int32 (harness converts int64)
    const float* __restrict__ feats,    // (3,512,512)
    const float* __restrict__ W1,       // (256,3)
    const float* __restrict__ b1,       // (256)
    const float* __restrict__ W2,       // (27,256)
    const float* __restrict__ b2,       // (27)
    float* __restrict__ out,            // (P)
    int P)
{
    __shared__ float sW1[HID][4];    // {w0,w1,w2,b1} per hidden unit, 16B rows
    __shared__ float sW2[HID][28];   // W2 transposed [hidden][k], padded to 28 (16B-aligned rows)

    const int tid = threadIdx.x;

    // cooperative staging
    for (int i = tid; i < HID; i += 256) {
        sW1[i][0] = W1[3 * i + 0];
        sW1[i][1] = W1[3 * i + 1];
        sW1[i][2] = W1[3 * i + 2];
        sW1[i][3] = b1[i];
    }
    for (int i = tid; i < HID * 28; i += 256) {
        const int j = i / 28;
        const int k = i - 28 * j;
        sW2[j][k] = (k < K27) ? W2[k * HID + j] : 0.0f;
    }
    __syncthreads();

    const int p = blockIdx.x * 256 + tid;
    if (p >= P) return;

    // load position (12B per thread, contiguous across the wave)
    const float p0 = pos[3 * p + 0];
    const float p1 = pos[3 * p + 1];
    const float p2 = pos[3 * p + 2];

    float lw[K27];
    #pragma unroll
    for (int k = 0; k < K27; ++k) lw[k] = b2[k];

    // MLP: 3 -> 256 -> 27, hidden dim streamed
    #pragma unroll 4
    for (int j = 0; j < HID; ++j) {
        const float4 w = *reinterpret_cast<const float4*>(&sW1[j][0]);
        float h = fmaf(p0, w.x, fmaf(p1, w.y, fmaf(p2, w.z, w.w)));
        h = (h > 0.0f) ? h : 0.01f * h;   // leaky_relu(0.01)
        #pragma unroll
        for (int k = 0; k < K27; ++k)
            lw[k] = fmaf(h, sW2[j][k], lw[k]);
    }

    // gather 3x3x3 neighborhood at mapping[p] and dot with lw
    const int my = mapping[2 * p + 0];
    const int mx = mapping[2 * p + 1];

    float acc = 0.0f;
    #pragma unroll
    for (int c = 0; c < 3; ++c) {
        #pragma unroll
        for (int dy = 0; dy < 3; ++dy) {
            const int y  = my + dy - 1;
            const int yc = min(max(y, 0), 511);
            const bool yok = ((unsigned)y < 512u);
            #pragma unroll
            for (int dx = 0; dx < 3; ++dx) {
                const int x  = mx + dx - 1;
                const int xc = min(max(x, 0), 511);
                float f = feats[(c * 512 + yc) * 512 + xc];   // always-valid address
                f = (yok && ((unsigned)x < 512u)) ? f : 0.0f; // zero-pad select
                acc = fmaf(lw[c * 9 + dy * 3 + dx], f, acc);
            }
        }
    }
    out[p] = acc;
}

extern "C" void kernel_launch(void* const* d_in, const int* in_sizes, int n_in,
                              void* d_out, int out_size, void* d_ws, size_t ws_size,
                              hipStream_t stream) {
    const float* pos     = (const float*)d_in[0];
    const int*   mapping = (const int*)d_in[1];
    const float* feats   = (const float*)d_in[2];
    // d_in[3] = depth, unused by the reference
    const float* W1      = (const float*)d_in[4];
    const float* b1      = (const float*)d_in[5];
    const float* W2      = (const float*)d_in[6];
    const float* b2      = (const float*)d_in[7];
    float* out = (float*)d_out;

    const int P = out_size;                 // 1024*1024
    const int blocks = (P + 255) / 256;
    mapnet_fused<<<blocks, 256, 0, stream>>>(pos, mapping, feats, W1, b1, W2, b2, out, P);
}